// Round 8
// baseline (184.690 us; speedup 1.0000x reference)
//
#include <hip/hip_runtime.h>

#define B_    2
#define N_TOK 2048
#define C_    1024
#define H_    16
#define D_    64
#define M_    (B_*N_TOK)   // 4096
#define N3C   3072

typedef unsigned short u16;
typedef unsigned int   u32;

typedef __attribute__((ext_vector_type(8))) short bf16x8;
typedef __attribute__((ext_vector_type(4))) float f32x4;

__device__ __forceinline__ u16 f2bf(float f) {       // RNE
  u32 u = __float_as_uint(f);
  return (u16)((u + 0x7FFFu + ((u >> 16) & 1u)) >> 16);
}

// packed fp32x2 -> bf16x2 (RNE), single VALU instr
__device__ __forceinline__ u32 cvtpk_bf16(float lo, float hi) {
  u32 r;
  asm("v_cvt_pk_bf16_f32 %0, %1, %2" : "=v"(r) : "v"(lo), "v"(hi));
  return r;
}

// async global->LDS, 16B/lane; LDS dest = wave-uniform base + lane*16
__device__ __forceinline__ void async16(const u16* g, u16* l) {
  __builtin_amdgcn_global_load_lds(
      (const __attribute__((address_space(1))) u32*)g,
      (__attribute__((address_space(3))) u32*)l, 16, 0, 0);
}

// ---------------- fused fp32 -> bf16 convert ----------------
__global__ void k_cvt(const float* __restrict__ x, const float* __restrict__ wq,
                      const float* __restrict__ wo,
                      u16* __restrict__ xb, u16* __restrict__ wqb, u16* __restrict__ wob) {
  size_t i = ((size_t)blockIdx.x * 256 + threadIdx.x) * 4;
  const size_t n0 = (size_t)M_ * C_;
  const size_t n1 = n0 + (size_t)N3C * C_;
  const float* s; u16* d;
  if (i < n0)      { s = x  + i;        d = xb  + i; }
  else if (i < n1) { s = wq + (i - n0); d = wqb + (i - n0); }
  else             { s = wo + (i - n1); d = wob + (i - n1); }
  float4 v = *(const float4*)s;
  *(ushort4*)d = make_ushort4(f2bf(v.x), f2bf(v.y), f2bf(v.z), f2bf(v.w));
}

// ---------------- GEMM1: qkv = x @ w_qkv^T + b   (BK=64, swizzled staging) ----------------
// 2-D grid dim3(32,24) (R6 showed XCD chunking regresses: L2/L3-resident regime).
// Q -> [B,H,N,D] pre-scaled by 0.125*log2(e).
// K -> blocked [bh][t32:64][c:8][row:32][e:8], rows PERMUTED: key w at row
//      p(w) = ((w>>2)&1)*16 + ((w>>3)&3)*4 + (w&3)  (makes S^T C-layout == K=32 A-frag).
// V -> [b,h,d,N], key-chunks XOR-swizzled: chunk' = ((t>>3)&7) ^ (d&7).
__global__ __launch_bounds__(256, 3) void k_gemm_qkv(
    const u16* __restrict__ A, const u16* __restrict__ Bm,
    const float* __restrict__ bias,
    u16* __restrict__ qout, u16* __restrict__ kout, u16* __restrict__ vout)
{
  __shared__ u16 As[128*64];   // 16 KB
  __shared__ u16 Bs[128*64];   // 16 KB
  const int K = C_;
  int bm = blockIdx.x, bn = blockIdx.y;
  int tid = threadIdx.x;
  int lane = tid & 63, wave = tid >> 6;
  int wrow = (wave >> 1) * 64, wcol = (wave & 1) * 64;
  int qd = lane >> 4, ln = lane & 15;

  f32x4 zero = {0.f, 0.f, 0.f, 0.f};
  f32x4 acc[4][4];
  for (int i = 0; i < 4; i++) for (int j = 0; j < 4; j++) acc[i][j] = zero;

  const u16* Ab = A  + (size_t)bm * 128 * K;
  const u16* Bb = Bm + (size_t)bn * 128 * K;

  for (int k0 = 0; k0 < K; k0 += 64) {
    __syncthreads();
    for (int j = 0; j < 4; j++) {
      int slot = (wave*4 + j)*64 + lane;
      int r = slot >> 3, kc = slot & 7;
      int c = (kc ^ (r & 7)) * 8;          // XOR swizzle (LDS dest is forced contiguous)
      async16(&Ab[(size_t)r * K + k0 + c], &As[(wave*4 + j) * 512]);
      async16(&Bb[(size_t)r * K + k0 + c], &Bs[(wave*4 + j) * 512]);
    }
    __syncthreads();
    for (int kk2 = 0; kk2 < 2; kk2++) {
      bf16x8 af[4], bfr[4];
      for (int mi = 0; mi < 4; mi++) {
        int row = wrow + mi*16 + ln;
        af[mi] = *(const bf16x8*)&As[(row*8 + ((kk2*4 + qd) ^ (ln & 7)))*8];
      }
      for (int ni = 0; ni < 4; ni++) {
        int row = wcol + ni*16 + ln;
        bfr[ni] = *(const bf16x8*)&Bs[(row*8 + ((kk2*4 + qd) ^ (ln & 7)))*8];
      }
      for (int mi = 0; mi < 4; mi++)
        for (int ni = 0; ni < 4; ni++)
          acc[mi][ni] = __builtin_amdgcn_mfma_f32_16x16x32_bf16(af[mi], bfr[ni], acc[mi][ni], 0, 0, 0);
    }
  }

  for (int ni = 0; ni < 4; ni++) {
    int nbase = bn*128 + wcol + ni*16 + ln;
    int three = nbase >> 10;        // wave-uniform
    int h = (nbase >> 6) & 15;
    int d = nbase & 63;
    float bv = bias[nbase];
    if (three == 2) {
      // V: [b,h,d,N] with XOR'd key chunks; 4 consecutive keys -> one 8B store
      for (int mi = 0; mi < 4; mi++) {
        int row0 = bm*128 + wrow + mi*16 + qd*4;
        int b = row0 >> 11, t0 = row0 & 2047;
        int chunkp = ((t0 >> 3) & 7) ^ (d & 7);
        u16 tmp[4];
        for (int r = 0; r < 4; r++) tmp[r] = f2bf(acc[mi][ni][r] + bv);
        size_t off = ((size_t)(b*H_ + h)*D_ + d)*N_TOK + (t0 >> 6)*64 + chunkp*8 + (t0 & 7);
        *(ushort4*)&vout[off] = *(ushort4*)tmp;
      }
    } else if (three == 1) {
      // K blocked, rows permuted by p(w)
      int c = d >> 3, e = d & 7;
      for (int mi = 0; mi < 4; mi++) {
        for (int r = 0; r < 4; r++) {
          int row = bm*128 + wrow + mi*16 + qd*4 + r;
          int b = row >> 11, t = row & 2047;
          int t32 = t >> 5, w = t & 31;
          int p = ((w >> 2) & 1)*16 + ((w >> 3) & 3)*4 + (w & 3);
          kout[((size_t)(b*H_ + h)*64 + t32)*2048 + (c*32 + p)*8 + e] = f2bf(acc[mi][ni][r] + bv);
        }
      }
    } else {
      float sc = 0.18033688011f;  // 0.125*log2(e) folded into Q
      for (int mi = 0; mi < 4; mi++) {
        for (int r = 0; r < 4; r++) {
          int row = bm*128 + wrow + mi*16 + qd*4 + r;
          int b = row >> 11, t = row & 2047;
          qout[(((size_t)(b*H_ + h))*N_TOK + t)*D_ + d] = f2bf((acc[mi][ni][r] + bv) * sc);
        }
      }
    }
  }
}

// ---------------- flash attention: 2-wave blocks, 4 barrier domains/CU ----------------
// grid 1024 x 128 threads (2 waves x 32 q-rows = 64 rows/block) -> 4 blocks/CU,
// same 8 waves/CU as before but 4 INDEPENDENT barrier domains (was 2): when one
// block sits in its stage->vmcnt(0) drain, three others have compute in flight.
// Per-wave math/layout byte-identical to the best-measured R4 kernel.
// Softmax VALU-minimized: ones-MFMA row-sums + v_cvt_pk_bf16_f32 P-packing.
__global__ __launch_bounds__(128, 4) void k_attn(
    const u16* __restrict__ Q, const u16* __restrict__ Kb, const u16* __restrict__ Vb,
    u16* __restrict__ Oa)   // [B*N][C] bf16
{
  __shared__ u16 Ks[4096];   // two 32-key tiles: [pair:2][c:8][row:32][e:8]
  __shared__ u16 Vs[4096];   // [d:64][chunk':8][e:8], chunk' = kc ^ (d&7)
  int ord = blockIdx.x;                 // 0..1023
  int xcd = ord & 7, kk = ord >> 3;     // kk: 0..127
  int bh = xcd * 4 + (kk & 3);          // 4 heads per XCD -> K/V L2-resident
  int qt = kk >> 2;                     // 0..31 (64-row Q tiles)
  int b = bh >> 4, h = bh & 15;
  int tid = threadIdx.x, lane = tid & 63, wave = tid >> 6;   // wave: 0..1
  int qd = lane >> 4, ln = lane & 15;

  const u16* Qg = Q  + ((size_t)bh * N_TOK + qt*64 + wave*32) * D_;
  const u16* Kg = Kb + (size_t)bh * 64 * 2048;
  const u16* Vg = Vb + (size_t)bh * (size_t)D_ * N_TOK;

  bf16x8 qf[2][2];
  for (int mi = 0; mi < 2; mi++)
    for (int ks = 0; ks < 2; ks++)
      qf[mi][ks] = *(const bf16x8*)&Qg[(mi*16 + ln)*D_ + ks*32 + qd*8];

  const short one_bf = (short)0x3F80;   // bf16 1.0
  bf16x8 ones = {one_bf, one_bf, one_bf, one_bf, one_bf, one_bf, one_bf, one_bf};

  f32x4 z = {0.f, 0.f, 0.f, 0.f};
  f32x4 oacc[2][4];
  f32x4 sumacc[2] = {z, z};             // P row-sums, same C-layout as oacc
  for (int mi = 0; mi < 2; mi++) for (int di = 0; di < 4; di++) oacc[mi][di] = z;

  for (int kt = 0; kt < 32; kt++) {     // 64 keys per iteration
    __syncthreads();
    const u16* Kt = Kg + (size_t)kt * 4096;   // two consecutive 32-key blocked tiles
    for (int j = 0; j < 4; j++) {             // 2 waves x 4 iters cover 512 slots
      int c0 = j*128 + wave*64;
      async16(&Kt[(c0 + lane)*8], &Ks[c0*8]);
      int cc = c0 + lane;
      int d = cc >> 3, kcp = cc & 7;          // LDS holds swizzled chunks as-is
      async16(&Vg[(size_t)d*N_TOK + kt*64 + kcp*8], &Vs[c0*8]);
    }
    __syncthreads();

    bf16x8 kf[4][2];
    for (int nt = 0; nt < 4; nt++)
      for (int ksd = 0; ksd < 2; ksd++)
        kf[nt][ksd] = *(const bf16x8*)&Ks[(nt>>1)*2048 + ((ksd*4 + qd)*32 + (nt&1)*16 + ln)*8];
    bf16x8 vf[4][2];
    for (int di = 0; di < 4; di++)
      for (int hf = 0; hf < 2; hf++) {
        int d = di*16 + ln;
        vf[di][hf] = *(const bf16x8*)&Vs[(d*8 + ((hf*4 + qd) ^ (ln & 7)))*8];
      }

    // S^T: rows = permuted key positions; sacc[mi][nt][r] at lane qd = key qd*8+(nt&1)*4+r of half nt>>1
    f32x4 sacc[2][4];
    for (int mi = 0; mi < 2; mi++)
      for (int nt = 0; nt < 4; nt++) {
        sacc[mi][nt] = z;
        for (int ksd = 0; ksd < 2; ksd++)
          sacc[mi][nt] = __builtin_amdgcn_mfma_f32_16x16x32_bf16(kf[nt][ksd], qf[mi][ksd], sacc[mi][nt], 0, 0, 0);
      }

    // P = exp2(S'); pack pairs with v_cvt_pk_bf16_f32; row-sum via ones-MFMA
    for (int mi = 0; mi < 2; mi++)
      for (int hf = 0; hf < 2; hf++) {
        union { u32 w[4]; bf16x8 v; } pk;
        pk.w[0] = cvtpk_bf16(__builtin_amdgcn_exp2f(sacc[mi][hf*2 + 0][0]),
                             __builtin_amdgcn_exp2f(sacc[mi][hf*2 + 0][1]));
        pk.w[1] = cvtpk_bf16(__builtin_amdgcn_exp2f(sacc[mi][hf*2 + 0][2]),
                             __builtin_amdgcn_exp2f(sacc[mi][hf*2 + 0][3]));
        pk.w[2] = cvtpk_bf16(__builtin_amdgcn_exp2f(sacc[mi][hf*2 + 1][0]),
                             __builtin_amdgcn_exp2f(sacc[mi][hf*2 + 1][1]));
        pk.w[3] = cvtpk_bf16(__builtin_amdgcn_exp2f(sacc[mi][hf*2 + 1][2]),
                             __builtin_amdgcn_exp2f(sacc[mi][hf*2 + 1][3]));
        sumacc[mi] = __builtin_amdgcn_mfma_f32_16x16x32_bf16(pk.v, ones, sumacc[mi], 0, 0, 0);
        for (int di = 0; di < 4; di++)
          oacc[mi][di] = __builtin_amdgcn_mfma_f32_16x16x32_bf16(pk.v, vf[di][hf], oacc[mi][di], 0, 0, 0);
      }
  }

  for (int mi = 0; mi < 2; mi++) {
    float rl[4];
    for (int r = 0; r < 4; r++)
      rl[r] = 1.0f / sumacc[mi][r];     // row-sum already in matching C-layout
    for (int di = 0; di < 4; di++)
      for (int r = 0; r < 4; r++) {
        int t = qt*64 + wave*32 + mi*16 + qd*4 + r;
        Oa[((size_t)b*N_TOK + t)*C_ + h*D_ + di*16 + ln] = f2bf(oacc[mi][di][r] * rl[r]);
      }
  }
}

// ---------------- GEMM2: out = attn @ w_out^T + b_out (fp32 out) ----------------
// 64x128 tile (2-D grid dim3(64,8) -> 2 blocks/CU), BK=64, XOR-swizzled
// staging/read (old linear layout was an 8-way ds_read bank conflict),
// double-buffered LDS, single barrier per K-step with issue-early staging.
__global__ __launch_bounds__(256, 2) void k_gemm_out(
    const u16* __restrict__ A, const u16* __restrict__ Bm,
    const float* __restrict__ bias, float* __restrict__ out)
{
  __shared__ u16 As[2][64*64];    // 8 KB x2
  __shared__ u16 Bs[2][128*64];   // 16 KB x2
  const int K = C_;
  int bm = blockIdx.x, bn = blockIdx.y;
  int tid = threadIdx.x;
  int lane = tid & 63, wave = tid >> 6;
  int wcol = wave * 32;
  int qd = lane >> 4, ln = lane & 15;

  f32x4 zero = {0.f, 0.f, 0.f, 0.f};
  f32x4 acc[4][2];
  for (int i = 0; i < 4; i++) for (int j = 0; j < 2; j++) acc[i][j] = zero;

  const u16* Ab = A  + (size_t)bm * 64 * K;
  const u16* Bb = Bm + (size_t)bn * 128 * K;

  auto stage = [&](int buf, int k0) {
    for (int j = 0; j < 2; j++) {            // A: 64x64 = 512 slots of 16B
      int slot = (wave*2 + j)*64 + lane;
      int r = slot >> 3, kc = slot & 7;
      int c = (kc ^ (r & 7)) * 8;            // XOR swizzle
      async16(&Ab[(size_t)r * K + k0 + c], &As[buf][(wave*2 + j) * 512]);
    }
    for (int j = 0; j < 4; j++) {            // B: 128x64 = 1024 slots
      int slot = (wave*4 + j)*64 + lane;
      int r = slot >> 3, kc = slot & 7;
      int c = (kc ^ (r & 7)) * 8;
      async16(&Bb[(size_t)r * K + k0 + c], &Bs[buf][(wave*4 + j) * 512]);
    }
  };

  stage(0, 0);
  __syncthreads();

  for (int t = 0; t < K/64; t++) {
    int cur = t & 1;
    if (t < K/64 - 1) stage(cur ^ 1, (t+1)*64);   // prefetch flies under MFMAs
    for (int kk2 = 0; kk2 < 2; kk2++) {
      bf16x8 af[4], bfr[2];
      for (int mi = 0; mi < 4; mi++) {
        int row = mi*16 + ln;
        af[mi] = *(const bf16x8*)&As[cur][(row*8 + ((kk2*4 + qd) ^ (ln & 7)))*8];
      }
      for (int ni = 0; ni < 2; ni++) {
        int row = wcol + ni*16 + ln;
        bfr[ni] = *(const bf16x8*)&Bs[cur][(row*8 + ((kk2*4 + qd) ^ (ln & 7)))*8];
      }
      for (int mi = 0; mi < 4; mi++)
        for (int ni = 0; ni < 2; ni++)
          acc[mi][ni] = __builtin_amdgcn_mfma_f32_16x16x32_bf16(af[mi], bfr[ni], acc[mi][ni], 0, 0, 0);
    }
    __syncthreads();
  }

  for (int ni = 0; ni < 2; ni++) {
    int col = bn*128 + wcol + ni*16 + ln;
    float bv = bias[col];
    for (int mi = 0; mi < 4; mi++)
      for (int r = 0; r < 4; r++) {
        int row = bm*64 + mi*16 + qd*4 + r;
        out[(size_t)row * C_ + col] = acc[mi][ni][r] + bv;
      }
  }
}

extern "C" void kernel_launch(void* const* d_in, const int* in_sizes, int n_in,
                              void* d_out, int out_size, void* d_ws, size_t ws_size,
                              hipStream_t stream) {
  const float* x     = (const float*)d_in[0];
  const float* w_qkv = (const float*)d_in[1];
  const float* b_qkv = (const float*)d_in[2];
  const float* w_out = (const float*)d_in[3];
  const float* b_out = (const float*)d_in[4];
  float* out = (float*)d_out;

  char* ws = (char*)d_ws;
  u16* x_bf    = (u16*)(ws);
  u16* wqkv_bf = (u16*)(ws + (size_t)8*1024*1024);
  u16* wout_bf = (u16*)(ws + (size_t)14*1024*1024);
  u16* q_bf    = (u16*)(ws + (size_t)16*1024*1024);  // [B,H,N,D], pre-scaled
  u16* k_bf    = (u16*)(ws + (size_t)24*1024*1024);  // blocked, rows permuted
  u16* v_bf    = (u16*)(ws + (size_t)32*1024*1024);  // [b,h,d,N], chunks XOR-swizzled
  u16* a_bf    = (u16*)(ws + (size_t)40*1024*1024);  // [M][C]

  k_cvt<<<8192, 256, 0, stream>>>(x, w_qkv, w_out, x_bf, wqkv_bf, wout_bf);
  k_gemm_qkv<<<dim3(32, 24), 256, 0, stream>>>(x_bf, wqkv_bf, b_qkv, q_bf, k_bf, v_bf);
  k_attn<<<1024, 128, 0, stream>>>(q_bf, k_bf, v_bf, a_bf);
  k_gemm_out<<<dim3(64, 8), 256, 0, stream>>>(a_bf, wout_bf, b_out, out);
}

// Round 9
// 167.554 us; speedup vs baseline: 1.1023x; 1.1023x over previous
//
#include <hip/hip_runtime.h>

#define B_    2
#define N_TOK 2048
#define C_    1024
#define H_    16
#define D_    64
#define M_    (B_*N_TOK)   // 4096
#define N3C   3072

typedef unsigned short u16;
typedef unsigned int   u32;

typedef __attribute__((ext_vector_type(8))) short bf16x8;
typedef __attribute__((ext_vector_type(4))) float f32x4;

__device__ __forceinline__ u16 f2bf(float f) {       // RNE
  u32 u = __float_as_uint(f);
  return (u16)((u + 0x7FFFu + ((u >> 16) & 1u)) >> 16);
}

// packed fp32x2 -> bf16x2 (RNE), single VALU instr
__device__ __forceinline__ u32 cvtpk_bf16(float lo, float hi) {
  u32 r;
  asm("v_cvt_pk_bf16_f32 %0, %1, %2" : "=v"(r) : "v"(lo), "v"(hi));
  return r;
}

// async global->LDS, 16B/lane; LDS dest = wave-uniform base + lane*16
__device__ __forceinline__ void async16(const u16* g, u16* l) {
  __builtin_amdgcn_global_load_lds(
      (const __attribute__((address_space(1))) u32*)g,
      (__attribute__((address_space(3))) u32*)l, 16, 0, 0);
}

// ---------------- fused fp32 -> bf16 convert ----------------
__global__ void k_cvt(const float* __restrict__ x, const float* __restrict__ wq,
                      const float* __restrict__ wo,
                      u16* __restrict__ xb, u16* __restrict__ wqb, u16* __restrict__ wob) {
  size_t i = ((size_t)blockIdx.x * 256 + threadIdx.x) * 4;
  const size_t n0 = (size_t)M_ * C_;
  const size_t n1 = n0 + (size_t)N3C * C_;
  const float* s; u16* d;
  if (i < n0)      { s = x  + i;        d = xb  + i; }
  else if (i < n1) { s = wq + (i - n0); d = wqb + (i - n0); }
  else             { s = wo + (i - n1); d = wob + (i - n1); }
  float4 v = *(const float4*)s;
  *(ushort4*)d = make_ushort4(f2bf(v.x), f2bf(v.y), f2bf(v.z), f2bf(v.w));
}

// ---------------- GEMM1: qkv = x @ w_qkv^T + b   (BK=64, swizzled staging) ----------------
// 2-D grid dim3(32,24): x-fastest dispatch shares the B-panel (bn) across
// consecutive blocks -- measured better than explicit XCD chunking (R6 regression:
// these working sets are L2/L3-resident, the T1-null regime).
// Q -> [B,H,N,D] pre-scaled by 0.125*log2(e).
// K -> blocked [bh][t32:64][c:8][row:32][e:8], rows PERMUTED: key w at row
//      p(w) = ((w>>2)&1)*16 + ((w>>3)&3)*4 + (w&3)  (makes S^T C-layout == K=32 A-frag).
// V -> [b,h,d,N], key-chunks XOR-swizzled: chunk' = ((t>>3)&7) ^ (d&7).
__global__ __launch_bounds__(256, 3) void k_gemm_qkv(
    const u16* __restrict__ A, const u16* __restrict__ Bm,
    const float* __restrict__ bias,
    u16* __restrict__ qout, u16* __restrict__ kout, u16* __restrict__ vout)
{
  __shared__ u16 As[128*64];   // 16 KB
  __shared__ u16 Bs[128*64];   // 16 KB
  const int K = C_;
  int bm = blockIdx.x, bn = blockIdx.y;
  int tid = threadIdx.x;
  int lane = tid & 63, wave = tid >> 6;
  int wrow = (wave >> 1) * 64, wcol = (wave & 1) * 64;
  int qd = lane >> 4, ln = lane & 15;

  f32x4 zero = {0.f, 0.f, 0.f, 0.f};
  f32x4 acc[4][4];
  for (int i = 0; i < 4; i++) for (int j = 0; j < 4; j++) acc[i][j] = zero;

  const u16* Ab = A  + (size_t)bm * 128 * K;
  const u16* Bb = Bm + (size_t)bn * 128 * K;

  for (int k0 = 0; k0 < K; k0 += 64) {
    __syncthreads();
    for (int j = 0; j < 4; j++) {
      int slot = (wave*4 + j)*64 + lane;
      int r = slot >> 3, kc = slot & 7;
      int c = (kc ^ (r & 7)) * 8;          // XOR swizzle (LDS dest is forced contiguous)
      async16(&Ab[(size_t)r * K + k0 + c], &As[(wave*4 + j) * 512]);
      async16(&Bb[(size_t)r * K + k0 + c], &Bs[(wave*4 + j) * 512]);
    }
    __syncthreads();
    for (int kk2 = 0; kk2 < 2; kk2++) {
      bf16x8 af[4], bfr[4];
      for (int mi = 0; mi < 4; mi++) {
        int row = wrow + mi*16 + ln;
        af[mi] = *(const bf16x8*)&As[(row*8 + ((kk2*4 + qd) ^ (ln & 7)))*8];
      }
      for (int ni = 0; ni < 4; ni++) {
        int row = wcol + ni*16 + ln;
        bfr[ni] = *(const bf16x8*)&Bs[(row*8 + ((kk2*4 + qd) ^ (ln & 7)))*8];
      }
      for (int mi = 0; mi < 4; mi++)
        for (int ni = 0; ni < 4; ni++)
          acc[mi][ni] = __builtin_amdgcn_mfma_f32_16x16x32_bf16(af[mi], bfr[ni], acc[mi][ni], 0, 0, 0);
    }
  }

  for (int ni = 0; ni < 4; ni++) {
    int nbase = bn*128 + wcol + ni*16 + ln;
    int three = nbase >> 10;        // wave-uniform
    int h = (nbase >> 6) & 15;
    int d = nbase & 63;
    float bv = bias[nbase];
    if (three == 2) {
      // V: [b,h,d,N] with XOR'd key chunks; 4 consecutive keys -> one 8B store
      for (int mi = 0; mi < 4; mi++) {
        int row0 = bm*128 + wrow + mi*16 + qd*4;
        int b = row0 >> 11, t0 = row0 & 2047;
        int chunkp = ((t0 >> 3) & 7) ^ (d & 7);
        u16 tmp[4];
        for (int r = 0; r < 4; r++) tmp[r] = f2bf(acc[mi][ni][r] + bv);
        size_t off = ((size_t)(b*H_ + h)*D_ + d)*N_TOK + (t0 >> 6)*64 + chunkp*8 + (t0 & 7);
        *(ushort4*)&vout[off] = *(ushort4*)tmp;
      }
    } else if (three == 1) {
      // K blocked, rows permuted by p(w)
      int c = d >> 3, e = d & 7;
      for (int mi = 0; mi < 4; mi++) {
        for (int r = 0; r < 4; r++) {
          int row = bm*128 + wrow + mi*16 + qd*4 + r;
          int b = row >> 11, t = row & 2047;
          int t32 = t >> 5, w = t & 31;
          int p = ((w >> 2) & 1)*16 + ((w >> 3) & 3)*4 + (w & 3);
          kout[((size_t)(b*H_ + h)*64 + t32)*2048 + (c*32 + p)*8 + e] = f2bf(acc[mi][ni][r] + bv);
        }
      }
    } else {
      float sc = 0.18033688011f;  // 0.125*log2(e) folded into Q
      for (int mi = 0; mi < 4; mi++) {
        for (int r = 0; r < 4; r++) {
          int row = bm*128 + wrow + mi*16 + qd*4 + r;
          int b = row >> 11, t = row & 2047;
          qout[(((size_t)(b*H_ + h))*N_TOK + t)*D_ + d] = f2bf((acc[mi][ni][r] + bv) * sc);
        }
      }
    }
  }
}

// ---------------- flash attention: KVBLK=64, VALU-minimized softmax (best measured) ----------------
// block = 4 waves x 32 q-rows = 128 rows; grid 512 (XCD-swizzled) -> 2 blocks/CU.
// Schedule variants all measured <= this simple 2-barrier form (dbuf-LDS -8%,
// reg-stage -7%, deferred-PV ~0%, KVBLK=128 -3%, 2-wave blocks -39%).
// Softmax VALU-minimized:
//  (1) row-sums via ones-column MFMA (sum lands in oacc's C-layout, no shuffles)
//  (2) v_cvt_pk_bf16_f32 P-packing.
__global__ __launch_bounds__(256, 2) void k_attn(
    const u16* __restrict__ Q, const u16* __restrict__ Kb, const u16* __restrict__ Vb,
    u16* __restrict__ Oa)   // [B*N][C] bf16
{
  __shared__ u16 Ks[4096];   // two 32-key tiles: [pair:2][c:8][row:32][e:8]
  __shared__ u16 Vs[4096];   // [d:64][chunk':8][e:8], chunk' = kc ^ (d&7)
  int ord = blockIdx.x;                 // 0..511
  int xcd = ord & 7, kk = ord >> 3;
  int bh = xcd * 4 + (kk & 3);          // 4 heads per XCD -> K/V L2-resident
  int qt = kk >> 2;                     // 0..15
  int b = bh >> 4, h = bh & 15;
  int tid = threadIdx.x, lane = tid & 63, wave = tid >> 6;
  int qd = lane >> 4, ln = lane & 15;

  const u16* Qg = Q  + ((size_t)bh * N_TOK + qt*128 + wave*32) * D_;
  const u16* Kg = Kb + (size_t)bh * 64 * 2048;
  const u16* Vg = Vb + (size_t)bh * (size_t)D_ * N_TOK;

  bf16x8 qf[2][2];
  for (int mi = 0; mi < 2; mi++)
    for (int ks = 0; ks < 2; ks++)
      qf[mi][ks] = *(const bf16x8*)&Qg[(mi*16 + ln)*D_ + ks*32 + qd*8];

  const short one_bf = (short)0x3F80;   // bf16 1.0
  bf16x8 ones = {one_bf, one_bf, one_bf, one_bf, one_bf, one_bf, one_bf, one_bf};

  f32x4 z = {0.f, 0.f, 0.f, 0.f};
  f32x4 oacc[2][4];
  f32x4 sumacc[2] = {z, z};             // P row-sums, same C-layout as oacc
  for (int mi = 0; mi < 2; mi++) for (int di = 0; di < 4; di++) oacc[mi][di] = z;

  for (int kt = 0; kt < 32; kt++) {     // 64 keys per iteration
    __syncthreads();
    const u16* Kt = Kg + (size_t)kt * 4096;   // two consecutive 32-key blocked tiles
    for (int j = 0; j < 2; j++) {
      int c0 = j*256 + wave*64;
      async16(&Kt[(c0 + lane)*8], &Ks[c0*8]);
      int cc = c0 + lane;
      int d = cc >> 3, kcp = cc & 7;          // LDS holds swizzled chunks as-is
      async16(&Vg[(size_t)d*N_TOK + kt*64 + kcp*8], &Vs[c0*8]);
    }
    __syncthreads();

    bf16x8 kf[4][2];
    for (int nt = 0; nt < 4; nt++)
      for (int ksd = 0; ksd < 2; ksd++)
        kf[nt][ksd] = *(const bf16x8*)&Ks[(nt>>1)*2048 + ((ksd*4 + qd)*32 + (nt&1)*16 + ln)*8];
    bf16x8 vf[4][2];
    for (int di = 0; di < 4; di++)
      for (int hf = 0; hf < 2; hf++) {
        int d = di*16 + ln;
        vf[di][hf] = *(const bf16x8*)&Vs[(d*8 + ((hf*4 + qd) ^ (ln & 7)))*8];
      }

    // S^T: rows = permuted key positions; sacc[mi][nt][r] at lane qd = key qd*8+(nt&1)*4+r of half nt>>1
    f32x4 sacc[2][4];
    for (int mi = 0; mi < 2; mi++)
      for (int nt = 0; nt < 4; nt++) {
        sacc[mi][nt] = z;
        for (int ksd = 0; ksd < 2; ksd++)
          sacc[mi][nt] = __builtin_amdgcn_mfma_f32_16x16x32_bf16(kf[nt][ksd], qf[mi][ksd], sacc[mi][nt], 0, 0, 0);
      }

    // P = exp2(S'); pack pairs with v_cvt_pk_bf16_f32; row-sum via ones-MFMA
    for (int mi = 0; mi < 2; mi++)
      for (int hf = 0; hf < 2; hf++) {
        union { u32 w[4]; bf16x8 v; } pk;
        pk.w[0] = cvtpk_bf16(__builtin_amdgcn_exp2f(sacc[mi][hf*2 + 0][0]),
                             __builtin_amdgcn_exp2f(sacc[mi][hf*2 + 0][1]));
        pk.w[1] = cvtpk_bf16(__builtin_amdgcn_exp2f(sacc[mi][hf*2 + 0][2]),
                             __builtin_amdgcn_exp2f(sacc[mi][hf*2 + 0][3]));
        pk.w[2] = cvtpk_bf16(__builtin_amdgcn_exp2f(sacc[mi][hf*2 + 1][0]),
                             __builtin_amdgcn_exp2f(sacc[mi][hf*2 + 1][1]));
        pk.w[3] = cvtpk_bf16(__builtin_amdgcn_exp2f(sacc[mi][hf*2 + 1][2]),
                             __builtin_amdgcn_exp2f(sacc[mi][hf*2 + 1][3]));
        sumacc[mi] = __builtin_amdgcn_mfma_f32_16x16x32_bf16(pk.v, ones, sumacc[mi], 0, 0, 0);
        for (int di = 0; di < 4; di++)
          oacc[mi][di] = __builtin_amdgcn_mfma_f32_16x16x32_bf16(pk.v, vf[di][hf], oacc[mi][di], 0, 0, 0);
      }
  }

  for (int mi = 0; mi < 2; mi++) {
    float rl[4];
    for (int r = 0; r < 4; r++)
      rl[r] = 1.0f / sumacc[mi][r];     // row-sum already in matching C-layout
    for (int di = 0; di < 4; di++)
      for (int r = 0; r < 4; r++) {
        int t = qt*128 + wave*32 + mi*16 + qd*4 + r;
        Oa[((size_t)b*N_TOK + t)*C_ + h*D_ + di*16 + ln] = f2bf(oacc[mi][di][r] * rl[r]);
      }
  }
}

// ---------------- GEMM2: out = attn @ w_out^T + b_out (fp32 out) ----------------
// 64x128 tile (2-D grid dim3(64,8) -> 2 blocks/CU), BK=64, XOR-swizzled
// staging/read (old linear layout was an 8-way ds_read bank conflict),
// double-buffered LDS, single barrier per K-step with issue-early staging.
__global__ __launch_bounds__(256, 2) void k_gemm_out(
    const u16* __restrict__ A, const u16* __restrict__ Bm,
    const float* __restrict__ bias, float* __restrict__ out)
{
  __shared__ u16 As[2][64*64];    // 8 KB x2
  __shared__ u16 Bs[2][128*64];   // 16 KB x2
  const int K = C_;
  int bm = blockIdx.x, bn = blockIdx.y;
  int tid = threadIdx.x;
  int lane = tid & 63, wave = tid >> 6;
  int wcol = wave * 32;
  int qd = lane >> 4, ln = lane & 15;

  f32x4 zero = {0.f, 0.f, 0.f, 0.f};
  f32x4 acc[4][2];
  for (int i = 0; i < 4; i++) for (int j = 0; j < 2; j++) acc[i][j] = zero;

  const u16* Ab = A  + (size_t)bm * 64 * K;
  const u16* Bb = Bm + (size_t)bn * 128 * K;

  auto stage = [&](int buf, int k0) {
    for (int j = 0; j < 2; j++) {            // A: 64x64 = 512 slots of 16B
      int slot = (wave*2 + j)*64 + lane;
      int r = slot >> 3, kc = slot & 7;
      int c = (kc ^ (r & 7)) * 8;            // XOR swizzle
      async16(&Ab[(size_t)r * K + k0 + c], &As[buf][(wave*2 + j) * 512]);
    }
    for (int j = 0; j < 4; j++) {            // B: 128x64 = 1024 slots
      int slot = (wave*4 + j)*64 + lane;
      int r = slot >> 3, kc = slot & 7;
      int c = (kc ^ (r & 7)) * 8;
      async16(&Bb[(size_t)r * K + k0 + c], &Bs[buf][(wave*4 + j) * 512]);
    }
  };

  stage(0, 0);
  __syncthreads();

  for (int t = 0; t < K/64; t++) {
    int cur = t & 1;
    if (t < K/64 - 1) stage(cur ^ 1, (t+1)*64);   // prefetch flies under MFMAs
    for (int kk2 = 0; kk2 < 2; kk2++) {
      bf16x8 af[4], bfr[2];
      for (int mi = 0; mi < 4; mi++) {
        int row = mi*16 + ln;
        af[mi] = *(const bf16x8*)&As[cur][(row*8 + ((kk2*4 + qd) ^ (ln & 7)))*8];
      }
      for (int ni = 0; ni < 2; ni++) {
        int row = wcol + ni*16 + ln;
        bfr[ni] = *(const bf16x8*)&Bs[cur][(row*8 + ((kk2*4 + qd) ^ (ln & 7)))*8];
      }
      for (int mi = 0; mi < 4; mi++)
        for (int ni = 0; ni < 2; ni++)
          acc[mi][ni] = __builtin_amdgcn_mfma_f32_16x16x32_bf16(af[mi], bfr[ni], acc[mi][ni], 0, 0, 0);
    }
    __syncthreads();
  }

  for (int ni = 0; ni < 2; ni++) {
    int col = bn*128 + wcol + ni*16 + ln;
    float bv = bias[col];
    for (int mi = 0; mi < 4; mi++)
      for (int r = 0; r < 4; r++) {
        int row = bm*64 + mi*16 + qd*4 + r;
        out[(size_t)row * C_ + col] = acc[mi][ni][r] + bv;
      }
  }
}

extern "C" void kernel_launch(void* const* d_in, const int* in_sizes, int n_in,
                              void* d_out, int out_size, void* d_ws, size_t ws_size,
                              hipStream_t stream) {
  const float* x     = (const float*)d_in[0];
  const float* w_qkv = (const float*)d_in[1];
  const float* b_qkv = (const float*)d_in[2];
  const float* w_out = (const float*)d_in[3];
  const float* b_out = (const float*)d_in[4];
  float* out = (float*)d_out;

  char* ws = (char*)d_ws;
  u16* x_bf    = (u16*)(ws);
  u16* wqkv_bf = (u16*)(ws + (size_t)8*1024*1024);
  u16* wout_bf = (u16*)(ws + (size_t)14*1024*1024);
  u16* q_bf    = (u16*)(ws + (size_t)16*1024*1024);  // [B,H,N,D], pre-scaled
  u16* k_bf    = (u16*)(ws + (size_t)24*1024*1024);  // blocked, rows permuted
  u16* v_bf    = (u16*)(ws + (size_t)32*1024*1024);  // [b,h,d,N], chunks XOR-swizzled
  u16* a_bf    = (u16*)(ws + (size_t)40*1024*1024);  // [M][C]

  k_cvt<<<8192, 256, 0, stream>>>(x, w_qkv, w_out, x_bf, wqkv_bf, wout_bf);
  k_gemm_qkv<<<dim3(32, 24), 256, 0, stream>>>(x_bf, wqkv_bf, b_qkv, q_bf, k_bf, v_bf);
  k_attn<<<512, 256, 0, stream>>>(q_bf, k_bf, v_bf, a_bf);
  k_gemm_out<<<dim3(64, 8), 256, 0, stream>>>(a_bf, wout_bf, b_out, out);
}

// Round 11
// 166.032 us; speedup vs baseline: 1.1124x; 1.0092x over previous
//
#include <hip/hip_runtime.h>

#define B_    2
#define N_TOK 2048
#define C_    1024
#define H_    16
#define D_    64
#define M_    (B_*N_TOK)   // 4096
#define N3C   3072

typedef unsigned short u16;
typedef unsigned int   u32;

typedef __attribute__((ext_vector_type(8))) short bf16x8;
typedef __attribute__((ext_vector_type(4))) float f32x4;

__device__ __forceinline__ u16 f2bf(float f) {       // RNE
  u32 u = __float_as_uint(f);
  return (u16)((u + 0x7FFFu + ((u >> 16) & 1u)) >> 16);
}

// packed fp32x2 -> bf16x2 (RNE), single VALU instr
__device__ __forceinline__ u32 cvtpk_bf16(float lo, float hi) {
  u32 r;
  asm("v_cvt_pk_bf16_f32 %0, %1, %2" : "=v"(r) : "v"(lo), "v"(hi));
  return r;
}

// async global->LDS, 16B/lane; LDS dest = wave-uniform base + lane*16
__device__ __forceinline__ void async16(const u16* g, u16* l) {
  __builtin_amdgcn_global_load_lds(
      (const __attribute__((address_space(1))) u32*)g,
      (__attribute__((address_space(3))) u32*)l, 16, 0, 0);
}

// ---------------- fused fp32 -> bf16 convert ----------------
__global__ void k_cvt(const float* __restrict__ x, const float* __restrict__ wq,
                      const float* __restrict__ wo,
                      u16* __restrict__ xb, u16* __restrict__ wqb, u16* __restrict__ wob) {
  size_t i = ((size_t)blockIdx.x * 256 + threadIdx.x) * 4;
  const size_t n0 = (size_t)M_ * C_;
  const size_t n1 = n0 + (size_t)N3C * C_;
  const float* s; u16* d;
  if (i < n0)      { s = x  + i;        d = xb  + i; }
  else if (i < n1) { s = wq + (i - n0); d = wqb + (i - n0); }
  else             { s = wo + (i - n1); d = wob + (i - n1); }
  float4 v = *(const float4*)s;
  *(ushort4*)d = make_ushort4(f2bf(v.x), f2bf(v.y), f2bf(v.z), f2bf(v.w));
}

// ---------------- GEMM1: qkv = x @ w_qkv^T + b   (BK=64, swizzled staging) ----------------
// 2-D grid dim3(32,24): x-fastest dispatch shares the B-panel (bn) across
// consecutive blocks -- measured better than explicit XCD chunking (R6 regression:
// these working sets are L2/L3-resident, the T1-null regime).
// Q -> [B,H,N,D] pre-scaled by 0.125*log2(e).
// K -> blocked [bh][t32:64][c:8][row:32][e:8], rows PERMUTED: key w at row
//      p(w) = ((w>>2)&1)*16 + ((w>>3)&3)*4 + (w&3)  (makes S^T C-layout == K=32 A-frag).
// V -> [b,h,d,N], key-chunks XOR-swizzled: chunk' = ((t>>3)&7) ^ (d&7).
__global__ __launch_bounds__(256, 3) void k_gemm_qkv(
    const u16* __restrict__ A, const u16* __restrict__ Bm,
    const float* __restrict__ bias,
    u16* __restrict__ qout, u16* __restrict__ kout, u16* __restrict__ vout)
{
  __shared__ u16 As[128*64];   // 16 KB
  __shared__ u16 Bs[128*64];   // 16 KB
  const int K = C_;
  int bm = blockIdx.x, bn = blockIdx.y;
  int tid = threadIdx.x;
  int lane = tid & 63, wave = tid >> 6;
  int wrow = (wave >> 1) * 64, wcol = (wave & 1) * 64;
  int qd = lane >> 4, ln = lane & 15;

  f32x4 zero = {0.f, 0.f, 0.f, 0.f};
  f32x4 acc[4][4];
  for (int i = 0; i < 4; i++) for (int j = 0; j < 4; j++) acc[i][j] = zero;

  const u16* Ab = A  + (size_t)bm * 128 * K;
  const u16* Bb = Bm + (size_t)bn * 128 * K;

  for (int k0 = 0; k0 < K; k0 += 64) {
    __syncthreads();
    for (int j = 0; j < 4; j++) {
      int slot = (wave*4 + j)*64 + lane;
      int r = slot >> 3, kc = slot & 7;
      int c = (kc ^ (r & 7)) * 8;          // XOR swizzle (LDS dest is forced contiguous)
      async16(&Ab[(size_t)r * K + k0 + c], &As[(wave*4 + j) * 512]);
      async16(&Bb[(size_t)r * K + k0 + c], &Bs[(wave*4 + j) * 512]);
    }
    __syncthreads();
    for (int kk2 = 0; kk2 < 2; kk2++) {
      bf16x8 af[4], bfr[4];
      for (int mi = 0; mi < 4; mi++) {
        int row = wrow + mi*16 + ln;
        af[mi] = *(const bf16x8*)&As[(row*8 + ((kk2*4 + qd) ^ (ln & 7)))*8];
      }
      for (int ni = 0; ni < 4; ni++) {
        int row = wcol + ni*16 + ln;
        bfr[ni] = *(const bf16x8*)&Bs[(row*8 + ((kk2*4 + qd) ^ (ln & 7)))*8];
      }
      for (int mi = 0; mi < 4; mi++)
        for (int ni = 0; ni < 4; ni++)
          acc[mi][ni] = __builtin_amdgcn_mfma_f32_16x16x32_bf16(af[mi], bfr[ni], acc[mi][ni], 0, 0, 0);
    }
  }

  for (int ni = 0; ni < 4; ni++) {
    int nbase = bn*128 + wcol + ni*16 + ln;
    int three = nbase >> 10;        // wave-uniform
    int h = (nbase >> 6) & 15;
    int d = nbase & 63;
    float bv = bias[nbase];
    if (three == 2) {
      // V: [b,h,d,N] with XOR'd key chunks; 4 consecutive keys -> one 8B store
      for (int mi = 0; mi < 4; mi++) {
        int row0 = bm*128 + wrow + mi*16 + qd*4;
        int b = row0 >> 11, t0 = row0 & 2047;
        int chunkp = ((t0 >> 3) & 7) ^ (d & 7);
        u16 tmp[4];
        for (int r = 0; r < 4; r++) tmp[r] = f2bf(acc[mi][ni][r] + bv);
        size_t off = ((size_t)(b*H_ + h)*D_ + d)*N_TOK + (t0 >> 6)*64 + chunkp*8 + (t0 & 7);
        *(ushort4*)&vout[off] = *(ushort4*)tmp;
      }
    } else if (three == 1) {
      // K blocked, rows permuted by p(w)
      int c = d >> 3, e = d & 7;
      for (int mi = 0; mi < 4; mi++) {
        for (int r = 0; r < 4; r++) {
          int row = bm*128 + wrow + mi*16 + qd*4 + r;
          int b = row >> 11, t = row & 2047;
          int t32 = t >> 5, w = t & 31;
          int p = ((w >> 2) & 1)*16 + ((w >> 3) & 3)*4 + (w & 3);
          kout[((size_t)(b*H_ + h)*64 + t32)*2048 + (c*32 + p)*8 + e] = f2bf(acc[mi][ni][r] + bv);
        }
      }
    } else {
      float sc = 0.18033688011f;  // 0.125*log2(e) folded into Q
      for (int mi = 0; mi < 4; mi++) {
        for (int r = 0; r < 4; r++) {
          int row = bm*128 + wrow + mi*16 + qd*4 + r;
          int b = row >> 11, t = row & 2047;
          qout[(((size_t)(b*H_ + h))*N_TOK + t)*D_ + d] = f2bf((acc[mi][ni][r] + bv) * sc);
        }
      }
    }
  }
}

// ---------------- flash attention: KVBLK=64, VALU-minimized softmax (best measured) ----------------
// block = 4 waves x 32 q-rows = 128 rows; grid 512 (XCD-swizzled) -> 2 blocks/CU.
// Verified-best structure: 2-barrier/iter LDS staging. Every variant measured
// worse or wrong: dbuf-LDS -8%, T14 reg-stage -7%, deferred-PV ~0%, KVBLK=128 -3%,
// 2-wave blocks -39%, direct-from-L2 (no LDS) FAILED correctness.
// Softmax VALU-minimized:
//  (1) row-sums via ones-column MFMA (sum lands in oacc's C-layout, no shuffles)
//  (2) v_cvt_pk_bf16_f32 P-packing.
__global__ __launch_bounds__(256, 2) void k_attn(
    const u16* __restrict__ Q, const u16* __restrict__ Kb, const u16* __restrict__ Vb,
    u16* __restrict__ Oa)   // [B*N][C] bf16
{
  __shared__ u16 Ks[4096];   // two 32-key tiles: [pair:2][c:8][row:32][e:8]
  __shared__ u16 Vs[4096];   // [d:64][chunk':8][e:8], chunk' = kc ^ (d&7)
  int ord = blockIdx.x;                 // 0..511
  int xcd = ord & 7, kk = ord >> 3;
  int bh = xcd * 4 + (kk & 3);          // 4 heads per XCD -> K/V L2-resident
  int qt = kk >> 2;                     // 0..15
  int b = bh >> 4, h = bh & 15;
  int tid = threadIdx.x, lane = tid & 63, wave = tid >> 6;
  int qd = lane >> 4, ln = lane & 15;

  const u16* Qg = Q  + ((size_t)bh * N_TOK + qt*128 + wave*32) * D_;
  const u16* Kg = Kb + (size_t)bh * 64 * 2048;
  const u16* Vg = Vb + (size_t)bh * (size_t)D_ * N_TOK;

  bf16x8 qf[2][2];
  for (int mi = 0; mi < 2; mi++)
    for (int ks = 0; ks < 2; ks++)
      qf[mi][ks] = *(const bf16x8*)&Qg[(mi*16 + ln)*D_ + ks*32 + qd*8];

  const short one_bf = (short)0x3F80;   // bf16 1.0
  bf16x8 ones = {one_bf, one_bf, one_bf, one_bf, one_bf, one_bf, one_bf, one_bf};

  f32x4 z = {0.f, 0.f, 0.f, 0.f};
  f32x4 oacc[2][4];
  f32x4 sumacc[2] = {z, z};             // P row-sums, same C-layout as oacc
  for (int mi = 0; mi < 2; mi++) for (int di = 0; di < 4; di++) oacc[mi][di] = z;

  for (int kt = 0; kt < 32; kt++) {     // 64 keys per iteration
    __syncthreads();
    const u16* Kt = Kg + (size_t)kt * 4096;   // two consecutive 32-key blocked tiles
    for (int j = 0; j < 2; j++) {
      int c0 = j*256 + wave*64;
      async16(&Kt[(c0 + lane)*8], &Ks[c0*8]);
      int cc = c0 + lane;
      int d = cc >> 3, kcp = cc & 7;          // LDS holds swizzled chunks as-is
      async16(&Vg[(size_t)d*N_TOK + kt*64 + kcp*8], &Vs[c0*8]);
    }
    __syncthreads();

    bf16x8 kf[4][2];
    for (int nt = 0; nt < 4; nt++)
      for (int ksd = 0; ksd < 2; ksd++)
        kf[nt][ksd] = *(const bf16x8*)&Ks[(nt>>1)*2048 + ((ksd*4 + qd)*32 + (nt&1)*16 + ln)*8];
    bf16x8 vf[4][2];
    for (int di = 0; di < 4; di++)
      for (int hf = 0; hf < 2; hf++) {
        int d = di*16 + ln;
        vf[di][hf] = *(const bf16x8*)&Vs[(d*8 + ((hf*4 + qd) ^ (ln & 7)))*8];
      }

    // S^T: rows = permuted key positions; sacc[mi][nt][r] at lane qd = key qd*8+(nt&1)*4+r of half nt>>1
    f32x4 sacc[2][4];
    for (int mi = 0; mi < 2; mi++)
      for (int nt = 0; nt < 4; nt++) {
        sacc[mi][nt] = z;
        for (int ksd = 0; ksd < 2; ksd++)
          sacc[mi][nt] = __builtin_amdgcn_mfma_f32_16x16x32_bf16(kf[nt][ksd], qf[mi][ksd], sacc[mi][nt], 0, 0, 0);
      }

    // P = exp2(S'); pack pairs with v_cvt_pk_bf16_f32; row-sum via ones-MFMA
    for (int mi = 0; mi < 2; mi++)
      for (int hf = 0; hf < 2; hf++) {
        union { u32 w[4]; bf16x8 v; } pk;
        pk.w[0] = cvtpk_bf16(__builtin_amdgcn_exp2f(sacc[mi][hf*2 + 0][0]),
                             __builtin_amdgcn_exp2f(sacc[mi][hf*2 + 0][1]));
        pk.w[1] = cvtpk_bf16(__builtin_amdgcn_exp2f(sacc[mi][hf*2 + 0][2]),
                             __builtin_amdgcn_exp2f(sacc[mi][hf*2 + 0][3]));
        pk.w[2] = cvtpk_bf16(__builtin_amdgcn_exp2f(sacc[mi][hf*2 + 1][0]),
                             __builtin_amdgcn_exp2f(sacc[mi][hf*2 + 1][1]));
        pk.w[3] = cvtpk_bf16(__builtin_amdgcn_exp2f(sacc[mi][hf*2 + 1][2]),
                             __builtin_amdgcn_exp2f(sacc[mi][hf*2 + 1][3]));
        sumacc[mi] = __builtin_amdgcn_mfma_f32_16x16x32_bf16(pk.v, ones, sumacc[mi], 0, 0, 0);
        for (int di = 0; di < 4; di++)
          oacc[mi][di] = __builtin_amdgcn_mfma_f32_16x16x32_bf16(pk.v, vf[di][hf], oacc[mi][di], 0, 0, 0);
      }
  }

  for (int mi = 0; mi < 2; mi++) {
    float rl[4];
    for (int r = 0; r < 4; r++)
      rl[r] = 1.0f / sumacc[mi][r];     // row-sum already in matching C-layout
    for (int di = 0; di < 4; di++)
      for (int r = 0; r < 4; r++) {
        int t = qt*128 + wave*32 + mi*16 + qd*4 + r;
        Oa[((size_t)b*N_TOK + t)*C_ + h*D_ + di*16 + ln] = f2bf(oacc[mi][di][r] * rl[r]);
      }
  }
}

// ---------------- GEMM2: out = attn @ w_out^T + b_out (fp32 out) ----------------
// 64x128 tile (2-D grid dim3(64,8) -> 2 blocks/CU), BK=64, XOR-swizzled
// staging/read (old linear layout was an 8-way ds_read bank conflict),
// double-buffered LDS, single barrier per K-step with issue-early staging.
__global__ __launch_bounds__(256, 2) void k_gemm_out(
    const u16* __restrict__ A, const u16* __restrict__ Bm,
    const float* __restrict__ bias, float* __restrict__ out)
{
  __shared__ u16 As[2][64*64];    // 8 KB x2
  __shared__ u16 Bs[2][128*64];   // 16 KB x2
  const int K = C_;
  int bm = blockIdx.x, bn = blockIdx.y;
  int tid = threadIdx.x;
  int lane = tid & 63, wave = tid >> 6;
  int wcol = wave * 32;
  int qd = lane >> 4, ln = lane & 15;

  f32x4 zero = {0.f, 0.f, 0.f, 0.f};
  f32x4 acc[4][2];
  for (int i = 0; i < 4; i++) for (int j = 0; j < 2; j++) acc[i][j] = zero;

  const u16* Ab = A  + (size_t)bm * 64 * K;
  const u16* Bb = Bm + (size_t)bn * 128 * K;

  auto stage = [&](int buf, int k0) {
    for (int j = 0; j < 2; j++) {            // A: 64x64 = 512 slots of 16B
      int slot = (wave*2 + j)*64 + lane;
      int r = slot >> 3, kc = slot & 7;
      int c = (kc ^ (r & 7)) * 8;            // XOR swizzle
      async16(&Ab[(size_t)r * K + k0 + c], &As[buf][(wave*2 + j) * 512]);
    }
    for (int j = 0; j < 4; j++) {            // B: 128x64 = 1024 slots
      int slot = (wave*4 + j)*64 + lane;
      int r = slot >> 3, kc = slot & 7;
      int c = (kc ^ (r & 7)) * 8;
      async16(&Bb[(size_t)r * K + k0 + c], &Bs[buf][(wave*4 + j) * 512]);
    }
  };

  stage(0, 0);
  __syncthreads();

  for (int t = 0; t < K/64; t++) {
    int cur = t & 1;
    if (t < K/64 - 1) stage(cur ^ 1, (t+1)*64);   // prefetch flies under MFMAs
    for (int kk2 = 0; kk2 < 2; kk2++) {
      bf16x8 af[4], bfr[2];
      for (int mi = 0; mi < 4; mi++) {
        int row = mi*16 + ln;
        af[mi] = *(const bf16x8*)&As[cur][(row*8 + ((kk2*4 + qd) ^ (ln & 7)))*8];
      }
      for (int ni = 0; ni < 2; ni++) {
        int row = wcol + ni*16 + ln;
        bfr[ni] = *(const bf16x8*)&Bs[cur][(row*8 + ((kk2*4 + qd) ^ (ln & 7)))*8];
      }
      for (int mi = 0; mi < 4; mi++)
        for (int ni = 0; ni < 2; ni++)
          acc[mi][ni] = __builtin_amdgcn_mfma_f32_16x16x32_bf16(af[mi], bfr[ni], acc[mi][ni], 0, 0, 0);
    }
    __syncthreads();
  }

  for (int ni = 0; ni < 2; ni++) {
    int col = bn*128 + wcol + ni*16 + ln;
    float bv = bias[col];
    for (int mi = 0; mi < 4; mi++)
      for (int r = 0; r < 4; r++) {
        int row = bm*64 + mi*16 + qd*4 + r;
        out[(size_t)row * C_ + col] = acc[mi][ni][r] + bv;
      }
  }
}

extern "C" void kernel_launch(void* const* d_in, const int* in_sizes, int n_in,
                              void* d_out, int out_size, void* d_ws, size_t ws_size,
                              hipStream_t stream) {
  const float* x     = (const float*)d_in[0];
  const float* w_qkv = (const float*)d_in[1];
  const float* b_qkv = (const float*)d_in[2];
  const float* w_out = (const float*)d_in[3];
  const float* b_out = (const float*)d_in[4];
  float* out = (float*)d_out;

  char* ws = (char*)d_ws;
  u16* x_bf    = (u16*)(ws);
  u16* wqkv_bf = (u16*)(ws + (size_t)8*1024*1024);
  u16* wout_bf = (u16*)(ws + (size_t)14*1024*1024);
  u16* q_bf    = (u16*)(ws + (size_t)16*1024*1024);  // [B,H,N,D], pre-scaled
  u16* k_bf    = (u16*)(ws + (size_t)24*1024*1024);  // blocked, rows permuted
  u16* v_bf    = (u16*)(ws + (size_t)32*1024*1024);  // [b,h,d,N], chunks XOR-swizzled
  u16* a_bf    = (u16*)(ws + (size_t)40*1024*1024);  // [M][C]

  k_cvt<<<8192, 256, 0, stream>>>(x, w_qkv, w_out, x_bf, wqkv_bf, wout_bf);
  k_gemm_qkv<<<dim3(32, 24), 256, 0, stream>>>(x_bf, wqkv_bf, b_qkv, q_bf, k_bf, v_bf);
  k_attn<<<512, 256, 0, stream>>>(q_bf, k_bf, v_bf, a_bf);
  k_gemm_out<<<dim3(64, 8), 256, 0, stream>>>(a_bf, wout_bf, b_out, out);
}